// Round 2
// baseline (561.650 us; speedup 1.0000x reference)
//
#include <hip/hip_runtime.h>
#include <hip/hip_bf16.h>
#include <math.h>

typedef __hip_bfloat16  bf16_t;
typedef __hip_bfloat162 bf162_t;

#define CDIM 128

static __device__ __forceinline__ float sigm(float x){ return 1.0f/(1.0f+__expf(-x)); }
static __device__ __forceinline__ float b2f(bf16_t v){ return __bfloat162float(v); }

// ---------- 1. LSTM single step -> evolved GCN weight w_new [C,C] (f32) ----------
__global__ void k_lstm(const float* __restrict__ weight, const float* __restrict__ w_ih,
                       const float* __restrict__ b_ih,   const float* __restrict__ b_hh,
                       float* __restrict__ wnew){
    __shared__ float wrow[CDIM];
    const int r = blockIdx.x, j = threadIdx.x;
    wrow[j] = weight[r*CDIM + j];
    __syncthreads();
    const float4* wi = (const float4*)(w_ih + (size_t)j*CDIM);            // i-gate row j
    const float4* wg = (const float4*)(w_ih + (size_t)(2*CDIM + j)*CDIM); // g-gate row
    const float4* wo = (const float4*)(w_ih + (size_t)(3*CDIM + j)*CDIM); // o-gate row
    const float4* wr = (const float4*)wrow;
    float si = 0.f, sg = 0.f, so = 0.f;
    #pragma unroll 8
    for(int k = 0; k < CDIM/4; k++){
        float4 w4 = wr[k];
        float4 a = wi[k]; si += w4.x*a.x + w4.y*a.y + w4.z*a.z + w4.w*a.w;
        float4 b = wg[k]; sg += w4.x*b.x + w4.y*b.y + w4.z*b.z + w4.w*b.w;
        float4 c = wo[k]; so += w4.x*c.x + w4.y*c.y + w4.z*c.z + w4.w*c.w;
    }
    si += b_ih[j]        + b_hh[j];
    sg += b_ih[2*CDIM+j] + b_hh[2*CDIM+j];
    so += b_ih[3*CDIM+j] + b_hh[3*CDIM+j];
    float c = sigm(si)*tanhf(sg);            // f-gate * c0 = 0
    wnew[r*CDIM + j] = sigm(so)*tanhf(c);
}

// ---------- 2. graph prep ----------
__global__ void k_init(int* __restrict__ deg, int* __restrict__ cursor, int* __restrict__ total, int n){
    int i = blockIdx.x*blockDim.x + threadIdx.x;
    if(i == 0) *total = 0;
    if(i < n){ deg[i] = 0; cursor[i] = 0; }
}

__global__ void k_count(const int* __restrict__ dst, int e, int* __restrict__ deg){
    int i = blockIdx.x*blockDim.x + threadIdx.x;
    if(i < e) atomicAdd(&deg[dst[i]], 1);
}

__global__ void k_off(const int* __restrict__ deg, float* __restrict__ dinv,
                      int* __restrict__ offs, int* __restrict__ total, int n){
    int i = blockIdx.x*blockDim.x + threadIdx.x;
    if(i < n){
        int d = deg[i];
        dinv[i] = rsqrtf((float)(d + 1));        // +1 self-loop
        offs[i] = atomicAdd(total, d);           // wave-scan + 1 atomic per wave (LLVM atomic optimizer)
    }
}

__global__ void k_fill(const int* __restrict__ src, const int* __restrict__ dst, int e,
                       const int* __restrict__ offs, int* __restrict__ cursor, int* __restrict__ csr){
    int i = blockIdx.x*blockDim.x + threadIdx.x;
    if(i < e){
        int d = dst[i];
        int p = offs[d] + atomicAdd(&cursor[d], 1);
        csr[p] = src[i];
    }
}

// ---------- 3. aggregate: agg[i] = dinv[i]*(dinv[i]*x[i] + sum_j dinv[j]*x[j]) ----------
static __device__ __forceinline__ void store_pair(float* p, int lane, float a, float b){
    ((float2*)p)[lane] = make_float2(a, b);
}
static __device__ __forceinline__ void store_pair(bf16_t* p, int lane, float a, float b){
    bf162_t v; v.x = __float2bfloat16(a); v.y = __float2bfloat16(b);
    ((bf162_t*)p)[lane] = v;
}

template<typename ST>
__global__ void k_agg(const float* __restrict__ x, const int* __restrict__ csr,
                      const int* __restrict__ offs, const int* __restrict__ deg,
                      const float* __restrict__ dinv, ST* __restrict__ agg, int n){
    int gw   = (int)(((size_t)blockIdx.x*blockDim.x + threadIdx.x) >> 6); // one wave per node
    int lane = threadIdx.x & 63;
    if(gw >= n) return;
    const int   off = offs[gw];
    const int   cnt = deg[gw];
    const float di  = dinv[gw];
    float2 sv = ((const float2*)(x + (size_t)gw*CDIM))[lane];
    float a0 = di*sv.x;
    float a1 = di*sv.y;
    for(int base = 0; base < cnt; base += 64){
        int m = cnt - base; if(m > 64) m = 64;
        int jid = 0; float djv = 0.f;
        if(lane < m){ jid = csr[off + base + lane]; djv = dinv[jid]; }
        for(int k = 0; k < m; k++){
            int   jj  = __shfl(jid, k, 64);
            float djj = __shfl(djv, k, 64);
            float2 v  = ((const float2*)(x + (size_t)jj*CDIM))[lane];
            a0 += djj*v.x;
            a1 += djj*v.y;
        }
    }
    a0 *= di; a1 *= di;
    store_pair(agg + (size_t)gw*CDIM, lane, a0, a1);
}

// ---------- 4. out = agg @ w_new (f32 out) ----------
static __device__ __forceinline__ float ld_f(float v){ return v; }
static __device__ __forceinline__ float ld_f(bf16_t v){ return __bfloat162float(v); }

template<typename LT>
__global__ void k_gemm(const LT* __restrict__ agg, const float* __restrict__ wnew,
                       float* __restrict__ out, int n){
    // wl2[kk][j] holds (w_new[2kk][j], w_new[2kk+1][j]) as bf16 pair.
    // lane j reads wl2[kk*128 + j]: 64 consecutive dwords -> 2-way bank alias (free).
    __shared__ bf162_t wl2[(CDIM/2)*CDIM];   // 32 KB
    __shared__ float   xs[2][CDIM];
    for(int t = threadIdx.x; t < (CDIM/2)*CDIM; t += blockDim.x){
        int kk = t >> 7, j = t & (CDIM-1);
        bf162_t v;
        v.x = __float2bfloat16(wnew[(2*kk  )*CDIM + j]);
        v.y = __float2bfloat16(wnew[(2*kk+1)*CDIM + j]);
        wl2[t] = v;
    }
    const int j  = threadIdx.x & (CDIM-1);
    const int ro = threadIdx.x >> 7;   // 0/1 (256 threads = 2 rows/iter); uniform per wave
    __syncthreads();
    for(int r0 = blockIdx.x*2; r0 < n; r0 += gridDim.x*2){
        int row = r0 + ro;
        if(row < n) xs[ro][j] = ld_f(agg[(size_t)row*CDIM + j]);
        __syncthreads();
        if(row < n){
            float acc = 0.f;
            #pragma unroll 8
            for(int kk = 0; kk < CDIM/2; kk++){
                bf162_t w = wl2[kk*CDIM + j];
                acc += xs[ro][2*kk]*b2f(w.x) + xs[ro][2*kk+1]*b2f(w.y);
            }
            out[(size_t)row*CDIM + j] = acc;
        }
        __syncthreads();
    }
}

extern "C" void kernel_launch(void* const* d_in, const int* in_sizes, int n_in,
                              void* d_out, int out_size, void* d_ws, size_t ws_size,
                              hipStream_t stream){
    const float* x      = (const float*)d_in[0];
    const int*   ei     = (const int*)  d_in[1];
    const float* weight = (const float*)d_in[2];
    const float* w_ih   = (const float*)d_in[3];
    // d_in[4] = w_hh: zero forward contribution (h0 = 0)
    const float* b_ih   = (const float*)d_in[5];
    const float* b_hh   = (const float*)d_in[6];
    float* out = (float*)d_out;

    const int n = in_sizes[0]/CDIM;   // 100000
    const int e = in_sizes[1]/2;      // 1600000
    const int* srcp = ei;
    const int* dstp = ei + e;

    auto alignup = [](size_t v){ return (v + 255) & ~(size_t)255; };
    char*  base = (char*)d_ws;
    size_t o = 0;
    float* wnew   = (float*)(base+o); o += alignup((size_t)CDIM*CDIM*sizeof(float));
    int*   deg    = (int*)  (base+o); o += alignup((size_t)n*4);
    float* dinv   = (float*)(base+o); o += alignup((size_t)n*4);
    int*   offs   = (int*)  (base+o); o += alignup((size_t)n*4);
    int*   cursor = (int*)  (base+o); o += alignup((size_t)n*4);
    int*   total  = (int*)  (base+o); o += alignup(256);
    int*   csr    = (int*)  (base+o); o += alignup((size_t)e*4);
    void*  aggbuf = (void*)(base+o);
    bool use_f32 = (ws_size >= o + (size_t)n*CDIM*sizeof(float));

    const int nb = (n + 255)/256;
    const int eb = (e + 255)/256;
    const int ab = (n + 3)/4;          // 4 waves (nodes) per 256-thread block

    k_lstm <<<CDIM, CDIM, 0, stream>>>(weight, w_ih, b_ih, b_hh, wnew);
    k_init <<<nb, 256, 0, stream>>>(deg, cursor, total, n);
    k_count<<<eb, 256, 0, stream>>>(dstp, e, deg);
    k_off  <<<nb, 256, 0, stream>>>(deg, dinv, offs, total, n);
    k_fill <<<eb, 256, 0, stream>>>(srcp, dstp, e, offs, cursor, csr);

    if(use_f32){
        k_agg<float> <<<ab, 256, 0, stream>>>(x, csr, offs, deg, dinv, (float*)aggbuf, n);
        k_gemm<float><<<2048, 256, 0, stream>>>((const float*)aggbuf, wnew, out, n);
    } else {
        k_agg<bf16_t> <<<ab, 256, 0, stream>>>(x, csr, offs, deg, dinv, (bf16_t*)aggbuf, n);
        k_gemm<bf16_t><<<2048, 256, 0, stream>>>((const bf16_t*)aggbuf, wnew, out, n);
    }
}

// Round 3
// 426.956 us; speedup vs baseline: 1.3155x; 1.3155x over previous
//
#include <hip/hip_runtime.h>
#include <hip/hip_bf16.h>
#include <math.h>

typedef __hip_bfloat16  bf16_t;
typedef __hip_bfloat162 bf162_t;
typedef __attribute__((ext_vector_type(8))) short  short8;   // 8 bf16 (4 VGPRs)
typedef __attribute__((ext_vector_type(4))) float  f32x4;

#define CDIM 128

static __device__ __forceinline__ float sigm(float x){ return 1.0f/(1.0f+__expf(-x)); }
static __device__ __forceinline__ short f2bf_s(float f){
    __hip_bfloat16 h = __float2bfloat16(f);
    return __builtin_bit_cast(short, h);
}

// ---------- 1. LSTM single step -> evolved GCN weight w_new [C,C] (f32) ----------
__global__ void k_lstm(const float* __restrict__ weight, const float* __restrict__ w_ih,
                       const float* __restrict__ b_ih,   const float* __restrict__ b_hh,
                       float* __restrict__ wnew){
    __shared__ float wrow[CDIM];
    const int r = blockIdx.x, j = threadIdx.x;
    wrow[j] = weight[r*CDIM + j];
    __syncthreads();
    const float4* wi = (const float4*)(w_ih + (size_t)j*CDIM);
    const float4* wg = (const float4*)(w_ih + (size_t)(2*CDIM + j)*CDIM);
    const float4* wo = (const float4*)(w_ih + (size_t)(3*CDIM + j)*CDIM);
    const float4* wr = (const float4*)wrow;
    float si = 0.f, sg = 0.f, so = 0.f;
    #pragma unroll 8
    for(int k = 0; k < CDIM/4; k++){
        float4 w4 = wr[k];
        float4 a = wi[k]; si += w4.x*a.x + w4.y*a.y + w4.z*a.z + w4.w*a.w;
        float4 b = wg[k]; sg += w4.x*b.x + w4.y*b.y + w4.z*b.z + w4.w*b.w;
        float4 c = wo[k]; so += w4.x*c.x + w4.y*c.y + w4.z*c.z + w4.w*c.w;
    }
    si += b_ih[j]        + b_hh[j];
    sg += b_ih[2*CDIM+j] + b_hh[2*CDIM+j];
    so += b_ih[3*CDIM+j] + b_hh[3*CDIM+j];
    float c = sigm(si)*tanhf(sg);            // f-gate * c0 = 0
    wnew[r*CDIM + j] = sigm(so)*tanhf(c);
}

// ---------- 1b. pack w_new into MFMA B-fragment layout (bf16) ----------
// wfrag[((t*8 + n0)*64 + lane)*8 + j] = bf16( W[32t + (lane>>4)*8 + j][16*n0 + (lane&15)] )
__global__ void k_pack(const float* __restrict__ wnew, short* __restrict__ wfrag){
    int id   = blockIdx.x*blockDim.x + threadIdx.x;   // 2048 total
    int lane = id & 63, n0 = (id >> 6) & 7, t = id >> 9;
    int quad = lane >> 4, mm = lane & 15;
    short8 v;
    #pragma unroll
    for(int j = 0; j < 8; j++)
        v[j] = f2bf_s(wnew[(32*t + quad*8 + j)*CDIM + 16*n0 + mm]);
    ((short8*)wfrag)[id] = v;
}

// ---------- 2. graph prep ----------
__global__ void k_init(int* __restrict__ deg, int* __restrict__ cursor, int* __restrict__ total, int n){
    int i = blockIdx.x*blockDim.x + threadIdx.x;
    if(i == 0) *total = 0;
    if(i < n){ deg[i] = 0; cursor[i] = 0; }
}

__global__ void k_count(const int* __restrict__ dst, int e, int* __restrict__ deg){
    int i = blockIdx.x*blockDim.x + threadIdx.x;
    if(i < e) atomicAdd(&deg[dst[i]], 1);
}

__global__ void k_off(const int* __restrict__ deg, float* __restrict__ dinv,
                      int* __restrict__ offs, int* __restrict__ total, int n){
    int i = blockIdx.x*blockDim.x + threadIdx.x;
    if(i < n){
        int d = deg[i];
        dinv[i] = rsqrtf((float)(d + 1));        // +1 self-loop
        offs[i] = atomicAdd(total, d);           // wave-aggregated scan by LLVM atomic optimizer
    }
}

__global__ void k_fill(const int* __restrict__ src, const int* __restrict__ dst, int e,
                       const int* __restrict__ offs, int* __restrict__ cursor, int* __restrict__ csr){
    int i = blockIdx.x*blockDim.x + threadIdx.x;
    if(i < e){
        int d = dst[i];
        int p = offs[d] + atomicAdd(&cursor[d], 1);
        csr[p] = src[i];
    }
}

// ---------- 3. aggregate: agg[i] = dinv[i]*(dinv[i]*x[i] + sum_j dinv[j]*x[j])  (bf16 out) ----------
__global__ void k_agg(const float* __restrict__ x, const int* __restrict__ csr,
                      const int* __restrict__ offs, const int* __restrict__ deg,
                      const float* __restrict__ dinv, bf16_t* __restrict__ agg, int n){
    int gw   = (int)(((size_t)blockIdx.x*blockDim.x + threadIdx.x) >> 6); // one wave per node
    int lane = threadIdx.x & 63;
    if(gw >= n) return;
    const int   off = offs[gw];
    const int   cnt = deg[gw];
    const float di  = dinv[gw];
    float2 sv = ((const float2*)(x + (size_t)gw*CDIM))[lane];
    float a0 = di*sv.x;
    float a1 = di*sv.y;
    for(int base = 0; base < cnt; base += 64){
        int m = cnt - base; if(m > 64) m = 64;
        int jid = 0; float djv = 0.f;
        if(lane < m){ jid = csr[off + base + lane]; djv = dinv[jid]; }
        for(int k = 0; k < m; k++){
            int   jj  = __shfl(jid, k, 64);
            float djj = __shfl(djv, k, 64);
            float2 v  = ((const float2*)(x + (size_t)jj*CDIM))[lane];
            a0 += djj*v.x;
            a1 += djj*v.y;
        }
    }
    a0 *= di; a1 *= di;
    bf162_t o; o.x = __float2bfloat16(a0); o.y = __float2bfloat16(a1);
    ((bf162_t*)(agg + (size_t)gw*CDIM))[lane] = o;
}

// ---------- 4. out = agg(bf16) @ W(bf16 frags) via MFMA, f32 out ----------
__global__ __launch_bounds__(256) void k_mgemm(const bf16_t* __restrict__ agg,
                                               const short* __restrict__ wfrag,
                                               float* __restrict__ out, int n){
    const int wid  = blockIdx.x*4 + (threadIdx.x >> 6);   // one wave per 16-row stripe
    const int row0 = wid*16;
    if(row0 >= n) return;
    const int lane = threadIdx.x & 63;
    const int m    = lane & 15, quad = lane >> 4;
    int arow = row0 + m; if(arow > n-1) arow = n-1;        // n%16==0 in practice
    const short* ap = (const short*)agg + (size_t)arow*CDIM + quad*8;
    short8 a0 = *(const short8*)(ap);        // k = 0  + quad*8 + [0,8)
    short8 a1 = *(const short8*)(ap + 32);   // k = 32 + ...
    short8 a2 = *(const short8*)(ap + 64);
    short8 a3 = *(const short8*)(ap + 96);
    const short8* bp = (const short8*)wfrag;
    float* orow = out + (size_t)(row0 + quad*4)*CDIM + m;
    const bool full = (row0 + 16 <= n);
    #pragma unroll
    for(int n0 = 0; n0 < 8; n0++){
        f32x4 acc = {0.f, 0.f, 0.f, 0.f};
        acc = __builtin_amdgcn_mfma_f32_16x16x32_bf16(a0, bp[(0*8+n0)*64 + lane], acc, 0, 0, 0);
        acc = __builtin_amdgcn_mfma_f32_16x16x32_bf16(a1, bp[(1*8+n0)*64 + lane], acc, 0, 0, 0);
        acc = __builtin_amdgcn_mfma_f32_16x16x32_bf16(a2, bp[(2*8+n0)*64 + lane], acc, 0, 0, 0);
        acc = __builtin_amdgcn_mfma_f32_16x16x32_bf16(a3, bp[(3*8+n0)*64 + lane], acc, 0, 0, 0);
        if(full){
            #pragma unroll
            for(int r = 0; r < 4; r++)
                orow[(size_t)r*CDIM + n0*16] = acc[r];    // row=quad*4+r, col=n0*16+m
        } else {
            #pragma unroll
            for(int r = 0; r < 4; r++)
                if(row0 + quad*4 + r < n) orow[(size_t)r*CDIM + n0*16] = acc[r];
        }
    }
}

extern "C" void kernel_launch(void* const* d_in, const int* in_sizes, int n_in,
                              void* d_out, int out_size, void* d_ws, size_t ws_size,
                              hipStream_t stream){
    const float* x      = (const float*)d_in[0];
    const int*   ei     = (const int*)  d_in[1];
    const float* weight = (const float*)d_in[2];
    const float* w_ih   = (const float*)d_in[3];
    // d_in[4] = w_hh: zero forward contribution (h0 = 0)
    const float* b_ih   = (const float*)d_in[5];
    const float* b_hh   = (const float*)d_in[6];
    float* out = (float*)d_out;

    const int n = in_sizes[0]/CDIM;   // 100000
    const int e = in_sizes[1]/2;      // 1600000
    const int* srcp = ei;
    const int* dstp = ei + e;

    auto alignup = [](size_t v){ return (v + 255) & ~(size_t)255; };
    char*  base = (char*)d_ws;
    size_t o = 0;
    float*  wnew   = (float*) (base+o); o += alignup((size_t)CDIM*CDIM*sizeof(float));
    short*  wfrag  = (short*) (base+o); o += alignup((size_t)CDIM*CDIM*sizeof(short));
    int*    deg    = (int*)   (base+o); o += alignup((size_t)n*4);
    float*  dinv   = (float*) (base+o); o += alignup((size_t)n*4);
    int*    offs   = (int*)   (base+o); o += alignup((size_t)n*4);
    int*    cursor = (int*)   (base+o); o += alignup((size_t)n*4);
    int*    total  = (int*)   (base+o); o += alignup(256);
    int*    csr    = (int*)   (base+o); o += alignup((size_t)e*4);
    bf16_t* aggbuf = (bf16_t*)(base+o); // n*CDIM*2 bytes

    const int nb = (n + 255)/256;
    const int eb = (e + 255)/256;
    const int ab = (n + 3)/4;                 // k_agg: 4 waves (nodes) per block
    const int gw = (n + 15)/16;               // k_mgemm: 16-row stripes
    const int gb = (gw + 3)/4;

    k_lstm <<<CDIM, CDIM, 0, stream>>>(weight, w_ih, b_ih, b_hh, wnew);
    k_pack <<<8, 256, 0, stream>>>(wnew, wfrag);
    k_init <<<nb, 256, 0, stream>>>(deg, cursor, total, n);
    k_count<<<eb, 256, 0, stream>>>(dstp, e, deg);
    k_off  <<<nb, 256, 0, stream>>>(deg, dinv, offs, total, n);
    k_fill <<<eb, 256, 0, stream>>>(srcp, dstp, e, offs, cursor, csr);
    k_agg  <<<ab, 256, 0, stream>>>(x, csr, offs, deg, dinv, aggbuf, n);
    k_mgemm<<<gb, 256, 0, stream>>>(aggbuf, wfrag, out, n);
}